// Round 8
// baseline (188.392 us; speedup 1.0000x reference)
//
#include <hip/hip_runtime.h>
#include <math.h>

typedef __bf16 bf16_t;
typedef __bf16 bf16x8 __attribute__((ext_vector_type(8)));
typedef __bf16 bf16x4 __attribute__((ext_vector_type(4)));
typedef float  floatx4 __attribute__((ext_vector_type(4)));

#define TT   4096
#define CD   1024
#define HSZ  64
#define NROW 16384
#define NEG_BIG (-1e30f)

// workspace element offsets (bf16)
#define WB_OFF 0                       // [kc][t12][512]  = 196608 elems
#define Q_OFF  196608                  // q[row][64]
#define K_OFF  (196608 + NROW * HSZ)   // K fragment tiles
#define V_OFF  (196608 + 2 * NROW * HSZ) // V fragment tiles

#if __has_builtin(__builtin_amdgcn_exp2f)
__device__ __forceinline__ float fexp2(float x) { return __builtin_amdgcn_exp2f(x); }
#else
__device__ __forceinline__ float fexp2(float x) { return exp2f(x); }
#endif

// cross-quad (lane ^16, ^32) reductions: a q-row's data lives on 4 lanes
__device__ __forceinline__ float qmax(float v) {
  v = fmaxf(v, __shfl_xor(v, 16));
  v = fmaxf(v, __shfl_xor(v, 32));
  return v;
}
__device__ __forceinline__ float qsum(float v) {
  v += __shfl_xor(v, 16);
  v += __shfl_xor(v, 32);
  return v;
}

// ---------------------------------------------------------------------------
// Kernel 0: fp32 weights -> bf16, layout [kc][t12][512] so a w-fragment for
// (kc, t12) is one contiguous 1 KB.
// Fragment elem (lane,j) = W_wsel[n = nt*16+(lane&15)][k = kc*32+(lane>>4)*8+j].
// ---------------------------------------------------------------------------
__global__ __launch_bounds__(256, 1) void wcvt_kernel(
    const float* __restrict__ Wk, const float* __restrict__ Wq,
    const float* __restrict__ Wv, bf16_t* __restrict__ Wb)
{
  const int t    = blockIdx.x * 256 + threadIdx.x;  // 192 blocks
  const int e    = t * 4;
  const int tile = e >> 9;          // 0..383
  const int kc   = tile / 12;
  const int t12  = tile - kc * 12;
  const int r    = e & 511;
  const int lane = r >> 3;
  const int j0   = r & 7;
  const int wsel = t12 >> 2;
  const int nt   = t12 & 3;
  const int n    = nt * 16 + (lane & 15);
  const int k    = kc * 32 + (lane >> 4) * 8 + j0;
  const float* src = (wsel == 0) ? Wq : (wsel == 1) ? Wk : Wv;
  float4 f = *(const float4*)(src + n * CD + k);
  bf16x4 o;
  o[0] = (bf16_t)f.x; o[1] = (bf16_t)f.y; o[2] = (bf16_t)f.z; o[3] = (bf16_t)f.w;
  *(bf16x4*)(Wb + e) = o;
}

// ---------------------------------------------------------------------------
// Kernel 1: QKV projection, BARRIER-FREE streaming form (round-3 empirical
// optimum, restored verbatim).  512 blocks x 256 threads (4 waves).  Block
// owns 32 x-rows (2 m-tiles); wave kh owns K-quarter kc = kh*8..kh*8+7.
// Per kc: 4 x-loads + 12 contiguous-1KB W-loads feeding 24 MFMAs; waves
// free-run (deep load queues).  End: 4-way partial-sum combine via LDS
// (1 barrier), kh=0 does the epilogue stores.
// K and V written in MFMA-fragment-contiguous tile layout (see attn).
// ---------------------------------------------------------------------------
__global__ __launch_bounds__(256, 2) void qkv_proj_kernel(
    const float* __restrict__ x, const bf16_t* __restrict__ Wb,
    bf16_t* __restrict__ qg, bf16_t* __restrict__ kfr, bf16_t* __restrict__ vfr)
{
  __shared__ __align__(16) floatx4 red[3][24][64];   // 72 KB combine buffer

  const int tid  = threadIdx.x;     // 0..255
  const int lane = tid & 63;
  const int kh   = tid >> 6;        // 0..3: K-quarter
  const int mr   = lane & 15;
  const int quad = lane >> 4;
  const int rt   = blockIdx.x;      // 0..511: 32-row group

  floatx4 acc[2][12];
#pragma unroll
  for (int mt = 0; mt < 2; ++mt)
#pragma unroll
    for (int i = 0; i < 12; ++i) acc[mt][i] = (floatx4){0.f, 0.f, 0.f, 0.f};

  const float* xp0 = x + (size_t)(rt * 32 + mr) * CD + quad * 8;
  const float* xp1 = xp0 + 16 * CD;

  for (int kc = kh * 8; kc < kh * 8 + 8; ++kc) {
    float4 a0 = *(const float4*)(xp0 + kc * 32);
    float4 a1 = *(const float4*)(xp0 + kc * 32 + 4);
    float4 b0 = *(const float4*)(xp1 + kc * 32);
    float4 b1 = *(const float4*)(xp1 + kc * 32 + 4);
    bf16x8 af0, af1;
    af0[0]=(bf16_t)a0.x; af0[1]=(bf16_t)a0.y; af0[2]=(bf16_t)a0.z; af0[3]=(bf16_t)a0.w;
    af0[4]=(bf16_t)a1.x; af0[5]=(bf16_t)a1.y; af0[6]=(bf16_t)a1.z; af0[7]=(bf16_t)a1.w;
    af1[0]=(bf16_t)b0.x; af1[1]=(bf16_t)b0.y; af1[2]=(bf16_t)b0.z; af1[3]=(bf16_t)b0.w;
    af1[4]=(bf16_t)b1.x; af1[5]=(bf16_t)b1.y; af1[6]=(bf16_t)b1.z; af1[7]=(bf16_t)b1.w;
    const bf16_t* wp = Wb + kc * 6144 + lane * 8;
#pragma unroll
    for (int i = 0; i < 12; ++i) {
      bf16x8 wf = *(const bf16x8*)(wp + i * 512);
      acc[0][i] = __builtin_amdgcn_mfma_f32_16x16x32_bf16(af0, wf, acc[0][i], 0, 0, 0);
      acc[1][i] = __builtin_amdgcn_mfma_f32_16x16x32_bf16(af1, wf, acc[1][i], 0, 0, 0);
    }
  }

  // ---- 4-way K-partial combine via LDS ----
  if (kh != 0) {
#pragma unroll
    for (int mt = 0; mt < 2; ++mt)
#pragma unroll
      for (int i = 0; i < 12; ++i)
        red[kh - 1][mt * 12 + i][lane] = acc[mt][i];
  }
  __syncthreads();
  if (kh == 0) {
    // ---- epilogue.  C/D: row = quad*4+reg (m -> trow), col = mr (n -> h) ----
    const float qscale = 0.18033688011112042f;  // 0.125 * log2(e)
#pragma unroll
    for (int mt = 0; mt < 2; ++mt) {
#pragma unroll
      for (int i = 0; i < 12; ++i) {
        floatx4 a = acc[mt][i];
        a += red[0][mt * 12 + i][lane];
        a += red[1][mt * 12 + i][lane];
        a += red[2][mt * 12 + i][lane];
        const int wsel = i >> 2;
        const int nt   = i & 3;
#pragma unroll
        for (int r = 0; r < 4; ++r) {
          const int trow = rt * 32 + mt * 16 + quad * 4 + r;
          const int h    = nt * 16 + mr;
          const float v  = a[r];
          if (wsel == 0) {
            qg[(size_t)trow * HSZ + h] = (bf16_t)(v * qscale);
          } else if (wsel == 1) {
            const size_t adr = ((((size_t)(trow >> 6)) * 4 + ((trow >> 4) & 3)) * 2
                                + (h >> 5)) * 512
                               + ((h >> 3) & 3) * 128 + (trow & 15) * 8 + (h & 7);
            kfr[adr] = (bf16_t)v;
          } else {
            const size_t adr = ((((size_t)(trow >> 6)) * 2 + ((trow >> 5) & 1)) * 4
                                + (h >> 4)) * 512
                               + ((trow >> 3) & 3) * 128 + (h & 15) * 8 + (trow & 7);
            vfr[adr] = (bf16_t)v;
          }
        }
      }
    }
  }
}

// ---------------------------------------------------------------------------
// Softmax over one S^T subtile.  Lane (mr,quad) holds, for q-row q=mr, the
// 16 scores kv = nt*16 + quad*4 + r in sv[nt][r]; the full 64-score row is
// spread over the 4 quads of the same mr.  Row max = in-lane tree + 2
// shfl_xor; l stays a per-lane partial (cross-quad summed once at combine).
// P^T written packed: bf16x4 per nt (kv-consecutive) -> 4 ds_write_b64.
// alpha==1 (no new max anywhere in the wave) skips the rescale exactly.
// ---------------------------------------------------------------------------
__device__ __forceinline__ void softmax_step(
    floatx4 (&sv)[4], float& mstv, float& lstv, floatx4 (&ov)[4],
    bf16_t* plp, const int mr, const int quad)
{
  float a = fmaxf(fmaxf(sv[0][0], sv[0][1]), fmaxf(sv[0][2], sv[0][3]));
  float b = fmaxf(fmaxf(sv[1][0], sv[1][1]), fmaxf(sv[1][2], sv[1][3]));
  float c = fmaxf(fmaxf(sv[2][0], sv[2][1]), fmaxf(sv[2][2], sv[2][3]));
  float d = fmaxf(fmaxf(sv[3][0], sv[3][1]), fmaxf(sv[3][2], sv[3][3]));
  float mx = fmaxf(fmaxf(a, b), fmaxf(c, d));
  mx = qmax(mx);
  const float mnew = fmaxf(mstv, mx);
  float rs = 0.f;
#pragma unroll
  for (int nt = 0; nt < 4; ++nt) {
    const float p0 = fexp2(sv[nt][0] - mnew);
    const float p1 = fexp2(sv[nt][1] - mnew);
    const float p2 = fexp2(sv[nt][2] - mnew);
    const float p3 = fexp2(sv[nt][3] - mnew);
    rs += (p0 + p1) + (p2 + p3);
    bf16x4 w;
    w[0] = (bf16_t)p0; w[1] = (bf16_t)p1; w[2] = (bf16_t)p2; w[3] = (bf16_t)p3;
    *(bf16x4*)(plp + mr * 72 + nt * 16 + quad * 4) = w;
  }
  if (__all(mx <= mstv)) {
    lstv += rs;                        // alpha == 1 exactly, skip rescale
  } else {
    const float alpha = fexp2(mstv - mnew);
    mstv = mnew;
    lstv = alpha * lstv + rs;
#pragma unroll
    for (int nt = 0; nt < 4; ++nt)
#pragma unroll
      for (int r = 0; r < 4; ++r) ov[nt][r] *= alpha;
  }
}

// ---------------------------------------------------------------------------
// Kernel 2: causal flash attention, S^T formulation + 1-deep K software
// pipeline.  256 blocks x 1024 thr (16 waves).  Block owns paired 32-row
// groups (gA=pr, gB=127-pr) of batch b = bid&3 (XCD-pinned K/V).  Waves
// partitioned between groups by KV work; each wave owns 32 q-rows (2
// subtiles sharing all K/V loads).
//   S^T = mfma(K, Q):  col(lane&15)=q, row(quad*4+reg)=kv  -> softmax row
//   reductions are in-lane + 2 shfl_xor, P^T is kv-consecutive in regs.
//   O^T = mfma(V, P^T): col(lane&15)=q, row(quad*4+reg)=h within tile nt.
// K pipeline: K(kt) lives in registers across the iteration; K(kt+nsplit)
// loads are issued right after the S-MFMAs consume K(kt), draining under
// softmax0 + V-loads + softmax1 + PV (~600-800 cy) -- removes the exposed
// L2/HBM latency that gated every iteration's S computation.
// ---------------------------------------------------------------------------
__global__ __launch_bounds__(1024, 4) void attn_kernel(
    const bf16_t* __restrict__ qg, const bf16_t* __restrict__ kfr,
    const bf16_t* __restrict__ vfr, float* __restrict__ out)
{
  __shared__ __align__(16) char smem[73728];            // plds U cmbo
  __shared__ float cml[16][16][2];
  bf16_t* plds = (bf16_t*)smem;                         // 16 x 2304 elems
  float (*cmbo)[16][68] = (float (*)[16][68])smem;      // [16][16][68]

  const int tid  = threadIdx.x;
  const int lane = tid & 63;
  const int wave = tid >> 6;     // 0..15
  const int mr   = lane & 15;
  const int quad = lane >> 4;

  const int bid = blockIdx.x;    // 0..255
  const int b   = bid & 3;
  const int pr  = bid >> 2;      // 0..63
  const int gA  = pr;
  const int gB  = 127 - pr;
  const int nAw = (gA >> 1) + 1;
  const int nBw = (gB >> 1) + 1;
  int na = (16 * nAw + ((nAw + nBw) >> 1)) / (nAw + nBw);
  na = na < 1 ? 1 : (na > 15 ? 15 : na);

  const bool inA   = wave < na;
  const int g      = inA ? gA : gB;
  const int slot   = inA ? wave : wave - na;
  const int nsplit = inA ? na : 16 - na;
  const int q0     = g * 32;
  const int ktmax  = g >> 1;

  const size_t baseq = (size_t)b * TT * HSZ;
  const bf16_t* kb = kfr + (size_t)b * 64 * 4096;   // 64 tiles x 4096 elems
  const bf16_t* vb = vfr + (size_t)b * 64 * 4096;

  bf16_t* pl0 = plds + wave * 2304;
  bf16_t* pl1 = pl0 + 1152;

  // Q fragments (used as MFMA B operand): lane&15 = q-row, elems = h
  bf16x8 qf[2][2];
#pragma unroll
  for (int s = 0; s < 2; ++s) {
    const bf16_t* qp = qg + baseq + (size_t)(q0 + s * 16 + mr) * HSZ + quad * 8;
    qf[s][0] = *(const bf16x8*)qp;
    qf[s][1] = *(const bf16x8*)(qp + 32);
  }

  floatx4 o0[4], o1[4];            // O^T: lane q=mr, h = nt*16+quad*4+r
#pragma unroll
  for (int i = 0; i < 4; ++i) {
    o0[i] = (floatx4){0.f, 0.f, 0.f, 0.f};
    o1[i] = (floatx4){0.f, 0.f, 0.f, 0.f};
  }
  float mst[2] = {NEG_BIG, NEG_BIG};   // per-lane row stats (row = mr)
  float lst[2] = {0.f, 0.f};           // per-lane PARTIAL row sum (16 kv)

  // ---- K pipeline prologue: load K(slot) ----
  bf16x8 kc0[4], kc1[4];
  if (slot <= ktmax) {
#pragma unroll
    for (int nt = 0; nt < 4; ++nt) {
      const bf16_t* kp = kb + ((size_t)slot * 4 + nt) * 1024 + lane * 8;
      kc0[nt] = *(const bf16x8*)kp;          // h 0..31
      kc1[nt] = *(const bf16x8*)(kp + 512);  // h 32..63
    }
  }

  for (int kt = slot; kt <= ktmax; kt += nsplit) {
    const int k0 = kt * 64;

    // ---- S^T for both subtiles from the in-register K(kt) ----
    floatx4 s0[4], s1[4];
#pragma unroll
    for (int i = 0; i < 4; ++i) {
      s0[i] = (floatx4){0.f, 0.f, 0.f, 0.f};
      s1[i] = (floatx4){0.f, 0.f, 0.f, 0.f};
    }
#pragma unroll
    for (int nt = 0; nt < 4; ++nt) {
      s0[nt] = __builtin_amdgcn_mfma_f32_16x16x32_bf16(kc0[nt], qf[0][0], s0[nt], 0, 0, 0);
      s0[nt] = __builtin_amdgcn_mfma_f32_16x16x32_bf16(kc1[nt], qf[0][1], s0[nt], 0, 0, 0);
      s1[nt] = __builtin_amdgcn_mfma_f32_16x16x32_bf16(kc0[nt], qf[1][0], s1[nt], 0, 0, 0);
      s1[nt] = __builtin_amdgcn_mfma_f32_16x16x32_bf16(kc1[nt], qf[1][1], s1[nt], 0, 0, 0);
    }

    // ---- issue K(kt+nsplit) loads; they drain under softmax+PV ----
    const int ktn = kt + nsplit;
    bf16x8 kn0[4], kn1[4];
    if (ktn <= ktmax) {
#pragma unroll
      for (int nt = 0; nt < 4; ++nt) {
        const bf16_t* kp = kb + ((size_t)ktn * 4 + nt) * 1024 + lane * 8;
        kn0[nt] = *(const bf16x8*)kp;
        kn1[nt] = *(const bf16x8*)(kp + 512);
      }
    }

    // ---- causal mask (last tile only): kv = k0+nt*16+quad*4+r, q = q0+mr ----
    if (kt == ktmax) {
      const int qa0 = q0 + mr;
#pragma unroll
      for (int nt = 0; nt < 4; ++nt) {
#pragma unroll
        for (int r = 0; r < 4; ++r) {
          const int kv = k0 + nt * 16 + quad * 4 + r;
          if (kv > qa0)      s0[nt][r] = NEG_BIG;
          if (kv > qa0 + 16) s1[nt][r] = NEG_BIG;
        }
      }
    }

    // ---- softmax subtile 0 -> P0^T (packed b64 stores) ----
    softmax_step(s0, mst[0], lst[0], o0, pl0, mr, quad);

    // ---- V fragment loads kc=0 (kv 0..31), contiguous 1 KB each ----
    bf16x8 vfa[4];
#pragma unroll
    for (int nt = 0; nt < 4; ++nt)
      vfa[nt] = *(const bf16x8*)(vb + ((size_t)kt * 8 + nt) * 512 + lane * 8);

    // ---- softmax subtile 1 -> P1^T ----
    softmax_step(s1, mst[1], lst[1], o1, pl1, mr, quad);

    bf16x8 vfb[4];                 // kc=1 (kv 32..63)
#pragma unroll
    for (int nt = 0; nt < 4; ++nt)
      vfb[nt] = *(const bf16x8*)(vb + ((size_t)kt * 8 + nt) * 512 + 2048 + lane * 8);

    // ---- O^T += V * P^T ----
    {
      bf16x8 pa0 = *(bf16x8*)&pl0[mr * 72 + quad * 8];
      bf16x8 pa1 = *(bf16x8*)&pl1[mr * 72 + quad * 8];
#pragma unroll
      for (int nt = 0; nt < 4; ++nt) {
        o0[nt] = __builtin_amdgcn_mfma_f32_16x16x32_bf16(vfa[nt], pa0, o0[nt], 0, 0, 0);
        o1[nt] = __builtin_amdgcn_mfma_f32_16x16x32_bf16(vfa[nt], pa1, o1[nt], 0, 0, 0);
      }
      bf16x8 pb0 = *(bf16x8*)&pl0[mr * 72 + 32 + quad * 8];
      bf16x8 pb1 = *(bf16x8*)&pl1[mr * 72 + 32 + quad * 8];
#pragma unroll
      for (int nt = 0; nt < 4; ++nt) {
        o0[nt] = __builtin_amdgcn_mfma_f32_16x16x32_bf16(vfb[nt], pb0, o0[nt], 0, 0, 0);
        o1[nt] = __builtin_amdgcn_mfma_f32_16x16x32_bf16(vfb[nt], pb1, o1[nt], 0, 0, 0);
      }
    }

    // ---- rotate K pipeline ----
    if (ktn <= ktmax) {
#pragma unroll
      for (int nt = 0; nt < 4; ++nt) { kc0[nt] = kn0[nt]; kc1[nt] = kn1[nt]; }
    }
  }

  // ---- combine: per group over its wave-slots, one subtile per pass ----
  __syncthreads();   // all PV reads of plds done (cmbo overlays it)
#pragma unroll
  for (int s = 0; s < 2; ++s) {
    const float lsum = qsum(lst[s]);   // cross-quad: full row sum
    if (lane < 16) {
      cml[wave][lane][0] = mst[s];
      cml[wave][lane][1] = lsum;
    }
    __syncthreads();
    {
      const int lo = inA ? 0 : na;
      const int hi = inA ? na : 16;
      float mstar = cml[lo][mr][0];
      for (int i = lo + 1; i < hi; ++i) mstar = fmaxf(mstar, cml[i][mr][0]);
      const float scale = fexp2(mst[s] - mstar);
#pragma unroll
      for (int nt = 0; nt < 4; ++nt) {
        floatx4 t;
#pragma unroll
        for (int r = 0; r < 4; ++r) t[r] = (s ? o1[nt][r] : o0[nt][r]) * scale;
        *(floatx4*)&cmbo[wave][mr][nt * 16 + quad * 4] = t;   // row=q, col=h
      }
    }
    __syncthreads();
    {
      const int grp = tid >> 9;            // 0 = A, 1 = B
      const int row = (tid >> 5) & 15;
      const int c0  = (tid & 31) * 2;
      const int lo  = grp ? na : 0;
      const int hi  = grp ? 16 : na;
      const int gq0 = (grp ? gB : gA) * 32 + s * 16;
      float mstar = cml[lo][row][0];
      for (int i = lo + 1; i < hi; ++i) mstar = fmaxf(mstar, cml[i][row][0]);
      float l = 0.f;
      for (int i = lo; i < hi; ++i)
        l += cml[i][row][1] * fexp2(cml[i][row][0] - mstar);
      float sx = 0.f, sy = 0.f;
      for (int i = lo; i < hi; ++i) {
        float2 v = *(float2*)&cmbo[i][row][c0];
        sx += v.x; sy += v.y;
      }
      const float invl = 1.0f / l;
      float2 res; res.x = sx * invl; res.y = sy * invl;
      *(float2*)(out + baseq + (size_t)(gq0 + row) * HSZ + c0) = res;
    }
    __syncthreads();   // cml/cmbo reused by next pass
  }
}

// ---------------------------------------------------------------------------
extern "C" void kernel_launch(void* const* d_in, const int* in_sizes, int n_in,
                              void* d_out, int out_size, void* d_ws, size_t ws_size,
                              hipStream_t stream) {
  const float* x  = (const float*)d_in[0];
  const float* Wk = (const float*)d_in[1];
  const float* Wq = (const float*)d_in[2];
  const float* Wv = (const float*)d_in[3];
  float* out = (float*)d_out;

  bf16_t* ws  = (bf16_t*)d_ws;
  bf16_t* Wb  = ws + WB_OFF;
  bf16_t* qg  = ws + Q_OFF;
  bf16_t* kfr = ws + K_OFF;
  bf16_t* vfr = ws + V_OFF;

  wcvt_kernel<<<dim3(192), dim3(256), 0, stream>>>(Wk, Wq, Wv, Wb);
  qkv_proj_kernel<<<dim3(512), dim3(256), 0, stream>>>(x, Wb, qg, kfr, vfr);
  attn_kernel<<<dim3(256), dim3(1024), 0, stream>>>(qg, kfr, vfr, out);
}

// Round 9
// 145.492 us; speedup vs baseline: 1.2949x; 1.2949x over previous
//
#include <hip/hip_runtime.h>
#include <math.h>

typedef __bf16 bf16_t;
typedef __bf16 bf16x8 __attribute__((ext_vector_type(8)));
typedef __bf16 bf16x4 __attribute__((ext_vector_type(4)));
typedef float  floatx4 __attribute__((ext_vector_type(4)));

#define TT   4096
#define CD   1024
#define HSZ  64
#define NROW 16384
#define NEG_BIG (-1e30f)

// workspace element offsets (bf16)
#define WB_OFF 0                       // [kc][t12][512]  = 196608 elems
#define Q_OFF  196608                  // q[row][64]
#define K_OFF  (196608 + NROW * HSZ)   // K fragment tiles
#define V_OFF  (196608 + 2 * NROW * HSZ) // V fragment tiles

#if __has_builtin(__builtin_amdgcn_exp2f)
__device__ __forceinline__ float fexp2(float x) { return __builtin_amdgcn_exp2f(x); }
#else
__device__ __forceinline__ float fexp2(float x) { return exp2f(x); }
#endif

// cross-quad (lane ^16, ^32) reductions: a q-row's data lives on 4 lanes
__device__ __forceinline__ float qmax(float v) {
  v = fmaxf(v, __shfl_xor(v, 16));
  v = fmaxf(v, __shfl_xor(v, 32));
  return v;
}
__device__ __forceinline__ float qsum(float v) {
  v += __shfl_xor(v, 16);
  v += __shfl_xor(v, 32);
  return v;
}

// ---------------------------------------------------------------------------
// Kernel 0: fp32 weights -> bf16, layout [kc][t12][512] so a w-fragment for
// (kc, t12) is one contiguous 1 KB.
// Fragment elem (lane,j) = W_wsel[n = nt*16+(lane&15)][k = kc*32+(lane>>4)*8+j].
// ---------------------------------------------------------------------------
__global__ __launch_bounds__(256, 1) void wcvt_kernel(
    const float* __restrict__ Wk, const float* __restrict__ Wq,
    const float* __restrict__ Wv, bf16_t* __restrict__ Wb)
{
  const int t    = blockIdx.x * 256 + threadIdx.x;  // 192 blocks
  const int e    = t * 4;
  const int tile = e >> 9;          // 0..383
  const int kc   = tile / 12;
  const int t12  = tile - kc * 12;
  const int r    = e & 511;
  const int lane = r >> 3;
  const int j0   = r & 7;
  const int wsel = t12 >> 2;
  const int nt   = t12 & 3;
  const int n    = nt * 16 + (lane & 15);
  const int k    = kc * 32 + (lane >> 4) * 8 + j0;
  const float* src = (wsel == 0) ? Wq : (wsel == 1) ? Wk : Wv;
  float4 f = *(const float4*)(src + n * CD + k);
  bf16x4 o;
  o[0] = (bf16_t)f.x; o[1] = (bf16_t)f.y; o[2] = (bf16_t)f.z; o[3] = (bf16_t)f.w;
  *(bf16x4*)(Wb + e) = o;
}

// ---------------------------------------------------------------------------
// Kernel 1: QKV projection, BARRIER-FREE streaming form (round-3 empirical
// optimum, verbatim).  512 blocks x 256 threads (4 waves).  Block owns 32
// x-rows (2 m-tiles); wave kh owns K-quarter kc = kh*8..kh*8+7.  Per kc:
// 4 x-loads + 12 contiguous-1KB W-loads feeding 24 MFMAs; waves free-run
// (deep load queues).  End: 4-way partial-sum combine via LDS (1 barrier),
// kh=0 does the epilogue stores.
// K and V written in MFMA-fragment-contiguous tile layout (see attn).
// ---------------------------------------------------------------------------
__global__ __launch_bounds__(256, 2) void qkv_proj_kernel(
    const float* __restrict__ x, const bf16_t* __restrict__ Wb,
    bf16_t* __restrict__ qg, bf16_t* __restrict__ kfr, bf16_t* __restrict__ vfr)
{
  __shared__ __align__(16) floatx4 red[3][24][64];   // 72 KB combine buffer

  const int tid  = threadIdx.x;     // 0..255
  const int lane = tid & 63;
  const int kh   = tid >> 6;        // 0..3: K-quarter
  const int mr   = lane & 15;
  const int quad = lane >> 4;
  const int rt   = blockIdx.x;      // 0..511: 32-row group

  floatx4 acc[2][12];
#pragma unroll
  for (int mt = 0; mt < 2; ++mt)
#pragma unroll
    for (int i = 0; i < 12; ++i) acc[mt][i] = (floatx4){0.f, 0.f, 0.f, 0.f};

  const float* xp0 = x + (size_t)(rt * 32 + mr) * CD + quad * 8;
  const float* xp1 = xp0 + 16 * CD;

  for (int kc = kh * 8; kc < kh * 8 + 8; ++kc) {
    float4 a0 = *(const float4*)(xp0 + kc * 32);
    float4 a1 = *(const float4*)(xp0 + kc * 32 + 4);
    float4 b0 = *(const float4*)(xp1 + kc * 32);
    float4 b1 = *(const float4*)(xp1 + kc * 32 + 4);
    bf16x8 af0, af1;
    af0[0]=(bf16_t)a0.x; af0[1]=(bf16_t)a0.y; af0[2]=(bf16_t)a0.z; af0[3]=(bf16_t)a0.w;
    af0[4]=(bf16_t)a1.x; af0[5]=(bf16_t)a1.y; af0[6]=(bf16_t)a1.z; af0[7]=(bf16_t)a1.w;
    af1[0]=(bf16_t)b0.x; af1[1]=(bf16_t)b0.y; af1[2]=(bf16_t)b0.z; af1[3]=(bf16_t)b0.w;
    af1[4]=(bf16_t)b1.x; af1[5]=(bf16_t)b1.y; af1[6]=(bf16_t)b1.z; af1[7]=(bf16_t)b1.w;
    const bf16_t* wp = Wb + kc * 6144 + lane * 8;
#pragma unroll
    for (int i = 0; i < 12; ++i) {
      bf16x8 wf = *(const bf16x8*)(wp + i * 512);
      acc[0][i] = __builtin_amdgcn_mfma_f32_16x16x32_bf16(af0, wf, acc[0][i], 0, 0, 0);
      acc[1][i] = __builtin_amdgcn_mfma_f32_16x16x32_bf16(af1, wf, acc[1][i], 0, 0, 0);
    }
  }

  // ---- 4-way K-partial combine via LDS ----
  if (kh != 0) {
#pragma unroll
    for (int mt = 0; mt < 2; ++mt)
#pragma unroll
      for (int i = 0; i < 12; ++i)
        red[kh - 1][mt * 12 + i][lane] = acc[mt][i];
  }
  __syncthreads();
  if (kh == 0) {
    // ---- epilogue.  C/D: row = quad*4+reg (m -> trow), col = mr (n -> h) ----
    const float qscale = 0.18033688011112042f;  // 0.125 * log2(e)
#pragma unroll
    for (int mt = 0; mt < 2; ++mt) {
#pragma unroll
      for (int i = 0; i < 12; ++i) {
        floatx4 a = acc[mt][i];
        a += red[0][mt * 12 + i][lane];
        a += red[1][mt * 12 + i][lane];
        a += red[2][mt * 12 + i][lane];
        const int wsel = i >> 2;
        const int nt   = i & 3;
#pragma unroll
        for (int r = 0; r < 4; ++r) {
          const int trow = rt * 32 + mt * 16 + quad * 4 + r;
          const int h    = nt * 16 + mr;
          const float v  = a[r];
          if (wsel == 0) {
            qg[(size_t)trow * HSZ + h] = (bf16_t)(v * qscale);
          } else if (wsel == 1) {
            const size_t adr = ((((size_t)(trow >> 6)) * 4 + ((trow >> 4) & 3)) * 2
                                + (h >> 5)) * 512
                               + ((h >> 3) & 3) * 128 + (trow & 15) * 8 + (h & 7);
            kfr[adr] = (bf16_t)v;
          } else {
            const size_t adr = ((((size_t)(trow >> 6)) * 2 + ((trow >> 5) & 1)) * 4
                                + (h >> 4)) * 512
                               + ((trow >> 3) & 3) * 128 + (h & 15) * 8 + (trow & 7);
            vfr[adr] = (bf16_t)v;
          }
        }
      }
    }
  }
}

// ---------------------------------------------------------------------------
// Softmax over one S^T subtile.  Lane (mr,quad) holds, for q-row q=mr, the
// 16 scores kv = nt*16 + quad*4 + r in sv[nt][r]; the full 64-score row is
// spread over the 4 quads of the same mr.  Row max = in-lane tree + 2
// shfl_xor; l stays a per-lane partial (cross-quad summed once at combine).
// P^T written packed: bf16x4 per nt (kv-consecutive) -> 4 ds_write_b64.
// alpha==1 (no new max anywhere in the wave) skips the rescale exactly.
// ---------------------------------------------------------------------------
__device__ __forceinline__ void softmax_step(
    floatx4 (&sv)[4], float& mstv, float& lstv, floatx4 (&ov)[4],
    bf16_t* plp, const int mr, const int quad)
{
  float a = fmaxf(fmaxf(sv[0][0], sv[0][1]), fmaxf(sv[0][2], sv[0][3]));
  float b = fmaxf(fmaxf(sv[1][0], sv[1][1]), fmaxf(sv[1][2], sv[1][3]));
  float c = fmaxf(fmaxf(sv[2][0], sv[2][1]), fmaxf(sv[2][2], sv[2][3]));
  float d = fmaxf(fmaxf(sv[3][0], sv[3][1]), fmaxf(sv[3][2], sv[3][3]));
  float mx = fmaxf(fmaxf(a, b), fmaxf(c, d));
  mx = qmax(mx);
  const float mnew = fmaxf(mstv, mx);
  float rs = 0.f;
#pragma unroll
  for (int nt = 0; nt < 4; ++nt) {
    const float p0 = fexp2(sv[nt][0] - mnew);
    const float p1 = fexp2(sv[nt][1] - mnew);
    const float p2 = fexp2(sv[nt][2] - mnew);
    const float p3 = fexp2(sv[nt][3] - mnew);
    rs += (p0 + p1) + (p2 + p3);
    bf16x4 w;
    w[0] = (bf16_t)p0; w[1] = (bf16_t)p1; w[2] = (bf16_t)p2; w[3] = (bf16_t)p3;
    *(bf16x4*)(plp + mr * 72 + nt * 16 + quad * 4) = w;
  }
  if (__all(mx <= mstv)) {
    lstv += rs;                        // alpha == 1 exactly, skip rescale
  } else {
    const float alpha = fexp2(mstv - mnew);
    mstv = mnew;
    lstv = alpha * lstv + rs;
#pragma unroll
    for (int nt = 0; nt < 4; ++nt)
#pragma unroll
      for (int r = 0; r < 4; ++r) ov[nt][r] *= alpha;
  }
}

// ---------------------------------------------------------------------------
// Kernel 2: causal flash attention, S^T formulation.  512 blocks x 1024 thr
// (16 waves), ONE 32-row group per block: g = 127 - (bid>>2) (heavy groups
// dispatched first for load balance), batch b = bid&3 (XCD-pinned K/V).
// All 16 waves split the group's kt range (slot = wave, nsplit = 16).
// Rationale: the old 256-block grid was exactly 1 block/CU, hard-capping
// occupancy at 16 waves (measured 36%) while VGPR=64 and LDS=75776 both
// permit 2 blocks/CU.  512 blocks makes 32 waves/CU schedulable -- 2x TLP
// for a latency-bound kernel -- with per-wave code unchanged.
//   S^T = mfma(K, Q):  col(lane&15)=q, row(quad*4+reg)=kv  -> softmax row
//   reductions are in-lane + 2 shfl_xor, P^T is kv-consecutive in regs.
//   O^T = mfma(V, P^T): col(lane&15)=q, row(quad*4+reg)=h within tile nt.
// ---------------------------------------------------------------------------
__global__ __launch_bounds__(1024, 4) void attn_kernel(
    const bf16_t* __restrict__ qg, const bf16_t* __restrict__ kfr,
    const bf16_t* __restrict__ vfr, float* __restrict__ out)
{
  __shared__ __align__(16) char smem[73728];            // plds U cmbo
  __shared__ float cml[16][16][2];
  bf16_t* plds = (bf16_t*)smem;                         // 16 x 2304 elems
  float (*cmbo)[16][68] = (float (*)[16][68])smem;      // [16][16][68]

  const int tid  = threadIdx.x;
  const int lane = tid & 63;
  const int wave = tid >> 6;     // 0..15
  const int mr   = lane & 15;
  const int quad = lane >> 4;

  const int bid = blockIdx.x;    // 0..511
  const int b   = bid & 3;
  const int g   = 127 - (bid >> 2);   // 0..127, heavy (large g) first
  const int q0  = g * 32;
  const int ktmax = g >> 1;

  const size_t baseq = (size_t)b * TT * HSZ;
  const bf16_t* kb = kfr + (size_t)b * 64 * 4096;   // 64 tiles x 4096 elems
  const bf16_t* vb = vfr + (size_t)b * 64 * 4096;

  bf16_t* pl0 = plds + wave * 2304;
  bf16_t* pl1 = pl0 + 1152;

  // Q fragments (used as MFMA B operand): lane&15 = q-row, elems = h
  bf16x8 qf[2][2];
#pragma unroll
  for (int s = 0; s < 2; ++s) {
    const bf16_t* qp = qg + baseq + (size_t)(q0 + s * 16 + mr) * HSZ + quad * 8;
    qf[s][0] = *(const bf16x8*)qp;
    qf[s][1] = *(const bf16x8*)(qp + 32);
  }

  floatx4 o0[4], o1[4];            // O^T: lane q=mr, h = nt*16+quad*4+r
#pragma unroll
  for (int i = 0; i < 4; ++i) {
    o0[i] = (floatx4){0.f, 0.f, 0.f, 0.f};
    o1[i] = (floatx4){0.f, 0.f, 0.f, 0.f};
  }
  float mst[2] = {NEG_BIG, NEG_BIG};   // per-lane row stats (row = mr)
  float lst[2] = {0.f, 0.f};           // per-lane PARTIAL row sum (16 kv)

  for (int kt = wave; kt <= ktmax; kt += 16) {
    const int k0 = kt * 64;

    // ---- S^T for both subtiles: mfma(K, Q).  K fragments = A operand ----
    floatx4 s0[4], s1[4];
#pragma unroll
    for (int i = 0; i < 4; ++i) {
      s0[i] = (floatx4){0.f, 0.f, 0.f, 0.f};
      s1[i] = (floatx4){0.f, 0.f, 0.f, 0.f};
    }
#pragma unroll
    for (int nt = 0; nt < 4; ++nt) {
      const bf16_t* kp = kb + ((size_t)kt * 4 + nt) * 1024 + lane * 8;
      bf16x8 kb0 = *(const bf16x8*)kp;          // h 0..31
      bf16x8 kb1 = *(const bf16x8*)(kp + 512);  // h 32..63
      s0[nt] = __builtin_amdgcn_mfma_f32_16x16x32_bf16(kb0, qf[0][0], s0[nt], 0, 0, 0);
      s0[nt] = __builtin_amdgcn_mfma_f32_16x16x32_bf16(kb1, qf[0][1], s0[nt], 0, 0, 0);
      s1[nt] = __builtin_amdgcn_mfma_f32_16x16x32_bf16(kb0, qf[1][0], s1[nt], 0, 0, 0);
      s1[nt] = __builtin_amdgcn_mfma_f32_16x16x32_bf16(kb1, qf[1][1], s1[nt], 0, 0, 0);
    }

    // ---- causal mask (last tile only): kv = k0+nt*16+quad*4+r, q = q0+mr ----
    if (kt == ktmax) {
      const int qa0 = q0 + mr;
#pragma unroll
      for (int nt = 0; nt < 4; ++nt) {
#pragma unroll
        for (int r = 0; r < 4; ++r) {
          const int kv = k0 + nt * 16 + quad * 4 + r;
          if (kv > qa0)      s0[nt][r] = NEG_BIG;
          if (kv > qa0 + 16) s1[nt][r] = NEG_BIG;
        }
      }
    }

    // ---- softmax subtile 0 -> P0^T (packed b64 stores) ----
    softmax_step(s0, mst[0], lst[0], o0, pl0, mr, quad);

    // ---- V fragment loads kc=0 (kv 0..31), contiguous 1 KB each ----
    bf16x8 vfa[4];
#pragma unroll
    for (int nt = 0; nt < 4; ++nt)
      vfa[nt] = *(const bf16x8*)(vb + ((size_t)kt * 8 + nt) * 512 + lane * 8);

    // ---- softmax subtile 1 -> P1^T ----
    softmax_step(s1, mst[1], lst[1], o1, pl1, mr, quad);

    bf16x8 vfb[4];                 // kc=1 (kv 32..63)
#pragma unroll
    for (int nt = 0; nt < 4; ++nt)
      vfb[nt] = *(const bf16x8*)(vb + ((size_t)kt * 8 + nt) * 512 + 2048 + lane * 8);

    // ---- O^T += V * P^T ----
    {
      bf16x8 pa0 = *(bf16x8*)&pl0[mr * 72 + quad * 8];
      bf16x8 pa1 = *(bf16x8*)&pl1[mr * 72 + quad * 8];
#pragma unroll
      for (int nt = 0; nt < 4; ++nt) {
        o0[nt] = __builtin_amdgcn_mfma_f32_16x16x32_bf16(vfa[nt], pa0, o0[nt], 0, 0, 0);
        o1[nt] = __builtin_amdgcn_mfma_f32_16x16x32_bf16(vfa[nt], pa1, o1[nt], 0, 0, 0);
      }
      bf16x8 pb0 = *(bf16x8*)&pl0[mr * 72 + 32 + quad * 8];
      bf16x8 pb1 = *(bf16x8*)&pl1[mr * 72 + 32 + quad * 8];
#pragma unroll
      for (int nt = 0; nt < 4; ++nt) {
        o0[nt] = __builtin_amdgcn_mfma_f32_16x16x32_bf16(vfb[nt], pb0, o0[nt], 0, 0, 0);
        o1[nt] = __builtin_amdgcn_mfma_f32_16x16x32_bf16(vfb[nt], pb1, o1[nt], 0, 0, 0);
      }
    }
  }

  // ---- combine over the 16 wave-slots, one subtile per pass ----
  __syncthreads();   // all PV reads of plds done (cmbo overlays it)
#pragma unroll
  for (int s = 0; s < 2; ++s) {
    const float lsum = qsum(lst[s]);   // cross-quad: full row sum
    if (lane < 16) {
      cml[wave][lane][0] = mst[s];
      cml[wave][lane][1] = lsum;
    }
    __syncthreads();
    {
      float mstar = cml[0][mr][0];
      for (int i = 1; i < 16; ++i) mstar = fmaxf(mstar, cml[i][mr][0]);
      const float scale = fexp2(mst[s] - mstar);   // 0 for empty waves
#pragma unroll
      for (int nt = 0; nt < 4; ++nt) {
        floatx4 t;
#pragma unroll
        for (int r = 0; r < 4; ++r) t[r] = (s ? o1[nt][r] : o0[nt][r]) * scale;
        *(floatx4*)&cmbo[wave][mr][nt * 16 + quad * 4] = t;   // row=q, col=h
      }
    }
    __syncthreads();
    {
      const int row = wave;           // 16 rows x 64 cols = 1024 threads
      const int col = lane;
      float mstar = cml[0][row][0];
      for (int i = 1; i < 16; ++i) mstar = fmaxf(mstar, cml[i][row][0]);
      float l = 0.f;
      for (int i = 0; i < 16; ++i)
        l += cml[i][row][1] * fexp2(cml[i][row][0] - mstar);
      float sx = 0.f;
      for (int i = 0; i < 16; ++i) sx += cmbo[i][row][col];
      out[baseq + (size_t)(q0 + s * 16 + row) * HSZ + col] = sx / l;
    }
    __syncthreads();   // cml/cmbo reused by next pass
  }
}

// ---------------------------------------------------------------------------
extern "C" void kernel_launch(void* const* d_in, const int* in_sizes, int n_in,
                              void* d_out, int out_size, void* d_ws, size_t ws_size,
                              hipStream_t stream) {
  const float* x  = (const float*)d_in[0];
  const float* Wk = (const float*)d_in[1];
  const float* Wq = (const float*)d_in[2];
  const float* Wv = (const float*)d_in[3];
  float* out = (float*)d_out;

  bf16_t* ws  = (bf16_t*)d_ws;
  bf16_t* Wb  = ws + WB_OFF;
  bf16_t* qg  = ws + Q_OFF;
  bf16_t* kfr = ws + K_OFF;
  bf16_t* vfr = ws + V_OFF;

  wcvt_kernel<<<dim3(192), dim3(256), 0, stream>>>(Wk, Wq, Wv, Wb);
  qkv_proj_kernel<<<dim3(512), dim3(256), 0, stream>>>(x, Wb, qg, kfr, vfr);
  attn_kernel<<<dim3(512), dim3(1024), 0, stream>>>(qg, kfr, vfr, out);
}